// Round 2
// baseline (202.231 us; speedup 1.0000x reference)
//
#include <hip/hip_runtime.h>

// ---------------------------------------------------------------------------
// DigitConvolutionalModel: x(32768,784) -> conv3x3(valid) -> 676
//   -> relu(@W1(676,300)+b1) -> relu(@W2(300,300)+b2) -> @W3(300,10)+b3
//
// R2 structure:
//  - conv folded into W1eff(784->800 padded, 300->320 padded), bf16 B-frag
//    order (16x16x32), built by prep kernel in d_ws.
//  - fused kernel: 512 blocks x 64 rows, 512 thr = 8 waves.
//    Wave w: m-half mh=w&1 (32 rows = 2 m-tiles), n-quarter nq=w>>1 (5 n-tiles).
//    A-frags: wave-private, straight from global x (fp32->bf16 cvt in regs),
//    register-prefetched -> no LDS/barriers for A.
//    B-frags: global_load_lds dwordx4 into 2x20KB LDS double buffer,
//    ONE barrier per K-chunk; stage(k+1) issued right after barrier(k) so it
//    has the whole compute phase before the next drain.
//    h1/h2 live in LDS (A-frag order), overlaid on the B1 double buffer.
// ---------------------------------------------------------------------------

typedef __bf16 bf16_t;
typedef __bf16 bf16x8 __attribute__((ext_vector_type(8)));
typedef float  f32x4  __attribute__((ext_vector_type(4)));

#define MFMA16(a, b, c) __builtin_amdgcn_mfma_f32_16x16x32_bf16((a), (b), (c), 0, 0, 0)

#define W1F_ELEMS (25 * 20 * 64 * 8)  // 256000  (K=800, N=320)
#define W2F_ELEMS (10 * 20 * 64 * 8)  // 102400  (K=320, N=320)
#define W3F_ELEMS (10 * 1 * 64 * 8)   // 5120    (K=320, N=16)

// ---------------------------------------------------------------------------
__global__ void prep_weights(const float* __restrict__ conv_w,
                             const float* __restrict__ W1,
                             const float* __restrict__ W2,
                             const float* __restrict__ W3,
                             bf16_t* __restrict__ W1f,
                             bf16_t* __restrict__ W2f,
                             bf16_t* __restrict__ W3f) {
    int idx = blockIdx.x * 256 + threadIdx.x;
    if (idx < 800 * 320) {
        int k = idx / 320;
        int n = idx - k * 320;
        float v = 0.0f;
        if (k < 784 && n < 300) {
            int py = k / 28;
            int px = k - py * 28;
#pragma unroll
            for (int ky = 0; ky < 3; ++ky) {
                int oy = py - ky;
                if (oy < 0 || oy > 25) continue;
#pragma unroll
                for (int kx = 0; kx < 3; ++kx) {
                    int ox = px - kx;
                    if (ox < 0 || ox > 25) continue;
                    v += conv_w[ky * 3 + kx] * W1[(oy * 26 + ox) * 300 + n];
                }
            }
        }
        int kc = k >> 5, quad = (k >> 3) & 3, j = k & 7;
        int nt = n >> 4, nin = n & 15;
        W1f[(((kc * 20 + nt) * 64 + quad * 16 + nin) << 3) + j] = (bf16_t)v;
    } else if (idx < 800 * 320 + 320 * 320) {
        int i2 = idx - 800 * 320;
        int k = i2 / 320;
        int n = i2 - k * 320;
        float v = (k < 300 && n < 300) ? W2[k * 300 + n] : 0.0f;
        int kc = k >> 5, quad = (k >> 3) & 3, j = k & 7;
        int nt = n >> 4, nin = n & 15;
        W2f[(((kc * 20 + nt) * 64 + quad * 16 + nin) << 3) + j] = (bf16_t)v;
    } else if (idx < 800 * 320 + 320 * 320 + 320 * 16) {
        int i3 = idx - (800 * 320 + 320 * 320);
        int k = i3 / 16;
        int n = i3 - k * 16;
        float v = (k < 300 && n < 10) ? W3[k * 10 + n] : 0.0f;
        int kc = k >> 5, quad = (k >> 3) & 3, j = k & 7;
        W3f[(((kc * 64) + quad * 16 + n) << 3) + j] = (bf16_t)v;
    }
}

// async global -> LDS, 16B per lane. lds ptr must be wave-uniform.
__device__ __forceinline__ void stage16(const bf16x8* g, bf16x8* l) {
    __builtin_amdgcn_global_load_lds(
        (const __attribute__((address_space(1))) void*)g,
        (__attribute__((address_space(3))) void*)l, 16, 0, 0);
}

// ---------------------------------------------------------------------------
// 64 rows/block, 512 threads = 8 waves. Wave w: mh=w&1 (rows mh*32..+31),
// nq=w>>1 (n-tiles nq*5..+4).
// A-frag (16x16x32): A[m=lane&15][k=(lane>>4)*8+j]
// C/D: col=lane&15, row=(lane>>4)*4+reg
// ---------------------------------------------------------------------------
__global__ __launch_bounds__(512, 4) void fused_mlp(
    const float* __restrict__ x, const float* __restrict__ b1,
    const float* __restrict__ b2, const float* __restrict__ b3,
    const bf16x8* __restrict__ W1f, const bf16x8* __restrict__ W2f,
    const bf16x8* __restrict__ W3f, float* __restrict__ out) {
    // 60 KB arena: [0,2560) bf16x8 = 40KB: B1 double buffer, later h-buf
    //              [2560,3840) = 20KB: B2 (GEMM2) / B3 (GEMM3)
    __shared__ bf16x8 arena[3840];
    bf16x8* bufB1 = arena;          // [2][20][64]
    bf16x8* hbuf  = arena;          // [10][4][64]
    bf16x8* bufB2 = arena + 2560;   // [20][64]

    const int tid = threadIdx.x;
    const int w   = tid >> 6;
    const int l   = tid & 63;
    const int mh  = w & 1;
    const int nq  = w >> 1;
    const int q   = l >> 4;
    const int l15 = l & 15;
    const int r0  = blockIdx.x * 64;

    const float* rowA = x + (size_t)(r0 + mh * 32 + l15) * 784;
    const float* rowB = rowA + 16 * 784;

    // preload biases for this wave's 5 n-tiles
    float bias1[5], bias2[5];
#pragma unroll
    for (int nt = 0; nt < 5; ++nt) {
        int n = (nq * 5 + nt) * 16 + l15;
        bias1[nt] = (n < 300) ? b1[n] : 0.0f;
        bias2[nt] = (n < 300) ? b2[n] : 0.0f;
    }
    float bias3 = (w < 4 && l15 < 10) ? b3[l15] : 0.0f;

    // prologue: stage W1 chunk 0 -> buf slot 0, W2 chunk 0 -> bufB2
    for (int t = w; t < 20; t += 8) stage16(W1f + (t * 64 + l), bufB1 + t * 64);
    for (int t = w; t < 20; t += 8) stage16(W2f + (t * 64 + l), bufB2 + t * 64);

    // A prefetch for chunk 0
    float4 ua0, ua1, ub0, ub1;
    {
        const float4* pa = (const float4*)(rowA + q * 8);
        const float4* pb = (const float4*)(rowB + q * 8);
        ua0 = pa[0]; ua1 = pa[1]; ub0 = pb[0]; ub1 = pb[1];
    }

    f32x4 acc[2][5];
#pragma unroll
    for (int m = 0; m < 2; ++m)
#pragma unroll
        for (int nt = 0; nt < 5; ++nt) acc[m][nt] = (f32x4){0.f, 0.f, 0.f, 0.f};

    // ---------------- GEMM1: 25 k32-chunks, ONE barrier per chunk ----------
    for (int kc = 0; kc < 25; ++kc) {
        __syncthreads();  // drain: stage(kc) + A(kc) landed; prev reads done

        if (kc + 1 < 25) {  // stage next chunk into other slot (in flight
                            // across the whole compute phase below)
            int s1 = (kc + 1) & 1;
            for (int t = w; t < 20; t += 8)
                stage16(W1f + (((kc + 1) * 20 + t) * 64 + l),
                        bufB1 + s1 * 1280 + t * 64);
        }

        // cvt A(kc) regs -> frags
        bf16x8 afA, afB;
        afA[0] = (bf16_t)ua0.x; afA[1] = (bf16_t)ua0.y;
        afA[2] = (bf16_t)ua0.z; afA[3] = (bf16_t)ua0.w;
        afA[4] = (bf16_t)ua1.x; afA[5] = (bf16_t)ua1.y;
        afA[6] = (bf16_t)ua1.z; afA[7] = (bf16_t)ua1.w;
        afB[0] = (bf16_t)ub0.x; afB[1] = (bf16_t)ub0.y;
        afB[2] = (bf16_t)ub0.z; afB[3] = (bf16_t)ub0.w;
        afB[4] = (bf16_t)ub1.x; afB[5] = (bf16_t)ub1.y;
        afB[6] = (bf16_t)ub1.z; afB[7] = (bf16_t)ub1.w;

        // prefetch A(kc+1)
        if (kc + 1 < 25) {
            int k0 = (kc + 1) * 32 + q * 8;
            if (k0 < 784) {
                const float4* pa = (const float4*)(rowA + k0);
                const float4* pb = (const float4*)(rowB + k0);
                ua0 = pa[0]; ua1 = pa[1]; ub0 = pb[0]; ub1 = pb[1];
            } else {
                ua0 = ua1 = ub0 = ub1 = make_float4(0.f, 0.f, 0.f, 0.f);
            }
        }

        const bf16x8* bb = bufB1 + (kc & 1) * 1280 + (nq * 5) * 64 + l;
#pragma unroll
        for (int nt = 0; nt < 5; ++nt) {
            bf16x8 b = bb[nt * 64];
            acc[0][nt] = MFMA16(afA, b, acc[0][nt]);
            acc[1][nt] = MFMA16(afB, b, acc[1][nt]);
        }
    }
    __syncthreads();  // everyone done with bufB1 before h overwrite

    // ---------------- h1 = relu(C1+b1) -> LDS (A-frag order) ---------------
    {
        bf16_t* hb = (bf16_t*)hbuf;
#pragma unroll
        for (int nt = 0; nt < 5; ++nt) {
            int n = (nq * 5 + nt) * 16 + l15;
            int kc2 = n >> 5, quad = (n >> 3) & 3, j = n & 7;
#pragma unroll
            for (int mt2 = 0; mt2 < 2; ++mt2) {
                int mt = mh * 2 + mt2;
#pragma unroll
                for (int r = 0; r < 4; ++r) {
                    float v = acc[mt2][nt][r] + bias1[nt];
                    v = v > 0.f ? v : 0.f;
                    hb[(((kc2 * 4 + mt) * 64 + quad * 16 + q * 4 + r) << 3) + j] =
                        (bf16_t)v;
                }
            }
        }
    }
    __syncthreads();

    // ---------------- GEMM2: 10 chunks; B2 single-buffer staged ------------
#pragma unroll
    for (int m = 0; m < 2; ++m)
#pragma unroll
        for (int nt = 0; nt < 5; ++nt) acc[m][nt] = (f32x4){0.f, 0.f, 0.f, 0.f};
    for (int kc = 0; kc < 10; ++kc) {
        bf16x8 a0 = hbuf[(kc * 4 + mh * 2 + 0) * 64 + l];
        bf16x8 a1 = hbuf[(kc * 4 + mh * 2 + 1) * 64 + l];
        const bf16x8* bb = bufB2 + (nq * 5) * 64 + l;
#pragma unroll
        for (int nt = 0; nt < 5; ++nt) {
            bf16x8 b = bb[nt * 64];
            acc[0][nt] = MFMA16(a0, b, acc[0][nt]);
            acc[1][nt] = MFMA16(a1, b, acc[1][nt]);
        }
        if (kc + 1 < 10) {
            __syncthreads();  // reads of chunk kc done
            for (int t = w; t < 20; t += 8)
                stage16(W2f + (((kc + 1) * 20 + t) * 64 + l), bufB2 + t * 64);
            __syncthreads();  // staged chunk kc+1 visible
        }
    }
    __syncthreads();  // last chunk's reads done before h2 overwrite

    // ---------------- h2 = relu(C2+b2) -> LDS ------------------------------
    {
        bf16_t* hb = (bf16_t*)hbuf;
#pragma unroll
        for (int nt = 0; nt < 5; ++nt) {
            int n = (nq * 5 + nt) * 16 + l15;
            int kc2 = n >> 5, quad = (n >> 3) & 3, j = n & 7;
#pragma unroll
            for (int mt2 = 0; mt2 < 2; ++mt2) {
                int mt = mh * 2 + mt2;
#pragma unroll
                for (int r = 0; r < 4; ++r) {
                    float v = acc[mt2][nt][r] + bias2[nt];
                    v = v > 0.f ? v : 0.f;
                    hb[(((kc2 * 4 + mt) * 64 + quad * 16 + q * 4 + r) << 3) + j] =
                        (bf16_t)v;
                }
            }
        }
    }
    __syncthreads();

    // ---------------- GEMM3: stage W3f (10KB), waves 0-3 compute -----------
    for (int t = w; t < 10; t += 8) stage16(W3f + (t * 64 + l), bufB2 + t * 64);
    __syncthreads();

    if (w < 4) {
        f32x4 acc3 = (f32x4){0.f, 0.f, 0.f, 0.f};
        for (int kc = 0; kc < 10; ++kc)
            acc3 = MFMA16(hbuf[(kc * 4 + w) * 64 + l], bufB2[kc * 64 + l], acc3);
        if (l15 < 10) {
#pragma unroll
            for (int r = 0; r < 4; ++r)
                out[(size_t)(r0 + w * 16 + q * 4 + r) * 10 + l15] = acc3[r] + bias3;
        }
    }
}

// ---------------------------------------------------------------------------
extern "C" void kernel_launch(void* const* d_in, const int* in_sizes, int n_in,
                              void* d_out, int out_size, void* d_ws, size_t ws_size,
                              hipStream_t stream) {
    const float* x      = (const float*)d_in[0];
    const float* conv_w = (const float*)d_in[1];
    const float* W1     = (const float*)d_in[2];
    const float* b1     = (const float*)d_in[3];
    const float* W2     = (const float*)d_in[4];
    const float* b2     = (const float*)d_in[5];
    const float* W3     = (const float*)d_in[6];
    const float* b3     = (const float*)d_in[7];
    float* out = (float*)d_out;

    char* ws = (char*)d_ws;
    bf16_t* W1f = (bf16_t*)(ws);
    bf16_t* W2f = (bf16_t*)(ws + (size_t)W1F_ELEMS * 2);
    bf16_t* W3f = (bf16_t*)(ws + (size_t)(W1F_ELEMS + W2F_ELEMS) * 2);
    if (ws_size < (size_t)(W1F_ELEMS + W2F_ELEMS + W3F_ELEMS) * 2) return;

    int prep_total = 800 * 320 + 320 * 320 + 320 * 16;  // 363520
    prep_weights<<<(prep_total + 255) / 256, 256, 0, stream>>>(
        conv_w, W1, W2, W3, W1f, W2f, W3f);

    fused_mlp<<<32768 / 64, 512, 0, stream>>>(
        x, b1, b2, b3, (const bf16x8*)W1f, (const bf16x8*)W2f,
        (const bf16x8*)W3f, out);
}